// Round 1
// baseline (265.145 us; speedup 1.0000x reference)
//
#include <hip/hip_runtime.h>
#include <math.h>

#define BB 512
#define NN 252
#define CC 256

__global__ __launch_bounds__(256) void detloss_main(const float* __restrict__ outp,
                                                    const float* __restrict__ tgtp,
                                                    float* __restrict__ acc) {
    __shared__ float s_c1[NN], s_c2[NN], s_c3[NN];
    __shared__ float s_red[5];
    __shared__ unsigned char s_fill[NN];
    __shared__ unsigned char s_mask[NN];

    const int b = blockIdx.x;
    const int tid = threadIdx.x;
    const float* ob = outp + (size_t)b * NN * CC;
    const float* tb = tgtp + (size_t)b * NN * CC;

    if (tid < NN) { s_c1[tid] = 0.f; s_c2[tid] = 0.f; s_c3[tid] = 0.f; s_fill[tid] = 0; }
    if (tid < 5) s_red[tid] = 0.f;
    __syncthreads();

    float bce_c = 0.f, ce_c = 0.f, lx_c = 0.f, ly_c = 0.f, lwh_c = 0.f;
    float4 o4 = make_float4(0.f, 0.f, 0.f, 0.f);
    bool m = false;

    // Phase A: BCE + scatter target coords by class index (per-batch permutation).
    if (tid < NN) {
        const float4 t4 = *(const float4*)(tb + (size_t)tid * CC);   // t0..t3
        const float tcls = tb[(size_t)tid * CC + 4];                 // class id (exact small int)
        o4 = *(const float4*)(ob + (size_t)tid * CC);                // p, x, y, wh
        const float t0 = t4.x;
        const float p = o4.x;
        bce_c = -(t0 * __logf(p) + (1.f - t0) * log1pf(-p));
        m = (t0 != 0.f);
        s_mask[tid] = m ? 1 : 0;
        if (m) {
            const int j = (int)tcls;          // unique per masked row (permutation)
            s_c1[j] = t4.y; s_c2[j] = t4.z; s_c3[j] = t4.w; s_fill[j] = 1;
        }
    }
    __syncthreads();

    if (tid < NN) {
        // Phase A2: MSE terms at slot j = tid (filtered row j vs scattered target).
        const float f1 = m ? o4.y : 0.f;
        const float f2 = m ? o4.z : 0.f;
        const float f3 = m ? o4.w : 0.f;
        const float d1 = f1 - s_c1[tid];
        const float d2 = f2 - s_c2[tid];
        const float d3 = sqrtf(f3) - sqrtf(s_c3[tid]);
        lx_c = d1 * d1; ly_c = d2 * d2; lwh_c = d3 * d3;

        // Phase B: column-wise logsumexp over n for channel k = tid.
        // Logits in [0,1) -> no max subtraction needed.
        const int k = tid;
        const float* cp = ob + 4 + k;
        float s = 0.f, diag = 0.f, x0 = 0.f;
        #pragma unroll 4
        for (int n = 0; n < NN; ++n) {
            const float v = cp[(size_t)n * CC];
            const float x = s_mask[n] ? v : 0.f;
            s += __expf(x);
            if (n == k) diag = x;   // logits[b,k,k]
            if (n == 0) x0 = x;     // logits[b,0,k]
        }
        const float lse = __logf(s);
        ce_c = lse - (s_fill[k] ? diag : x0);   // -picked
    }

    // Wave-64 shuffle reduction, then one LDS atomic per wave, then 5 global atomics per block.
    #pragma unroll
    for (int off = 32; off > 0; off >>= 1) {
        bce_c += __shfl_down(bce_c, off);
        ce_c  += __shfl_down(ce_c,  off);
        lx_c  += __shfl_down(lx_c,  off);
        ly_c  += __shfl_down(ly_c,  off);
        lwh_c += __shfl_down(lwh_c, off);
    }
    if ((tid & 63) == 0) {
        atomicAdd(&s_red[0], bce_c);
        atomicAdd(&s_red[1], ce_c);
        atomicAdd(&s_red[2], lx_c);
        atomicAdd(&s_red[3], ly_c);
        atomicAdd(&s_red[4], lwh_c);
    }
    __syncthreads();
    if (tid < 5) atomicAdd(&acc[tid], s_red[tid]);
}

__global__ void detloss_final(const float* __restrict__ acc, float* __restrict__ outv) {
    const float inv = 1.0f / (float)(BB * NN);
    const float bce = acc[0] * inv;
    const float ce  = acc[1] * inv;
    const float lx  = acc[2] * inv;
    const float ly  = acc[3] * inv;
    const float lwh = acc[4] * inv;
    const float mse = lx + ly + 2.f * lwh;
    outv[0] = 10.f * mse + bce + 0.5f * (1.f - bce) + ce;
}

extern "C" void kernel_launch(void* const* d_in, const int* in_sizes, int n_in,
                              void* d_out, int out_size, void* d_ws, size_t ws_size,
                              hipStream_t stream) {
    const float* outp = (const float*)d_in[0];
    const float* tgtp = (const float*)d_in[1];
    float* acc = (float*)d_ws;
    hipMemsetAsync(acc, 0, 5 * sizeof(float), stream);
    detloss_main<<<BB, 256, 0, stream>>>(outp, tgtp, acc);
    detloss_final<<<1, 1, 0, stream>>>(acc, (float*)d_out);
}

// Round 2
// 249.118 us; speedup vs baseline: 1.0643x; 1.0643x over previous
//
#include <hip/hip_runtime.h>
#include <math.h>

#define BB 512
#define NN 252
#define CC 256
#define NW 16   // waves per block (1024 threads)

__global__ __launch_bounds__(1024) void detloss_main(const float* __restrict__ outp,
                                                     const float* __restrict__ tgtp,
                                                     float* __restrict__ acc) {
    __shared__ float s_c1[NN], s_c2[NN], s_c3[NN];
    __shared__ float s_diag[NN], s_row0[NN];
    __shared__ float s_part[NW * NN];
    __shared__ float s_red[5];
    __shared__ int s_mask[NN];
    __shared__ int s_fill[NN];
    __shared__ int s_cnt;

    const int b = blockIdx.x;
    const int tid = threadIdx.x;
    const float* ob = outp + (size_t)b * NN * CC;
    const float* tb = tgtp + (size_t)b * NN * CC;

    if (tid < NN) {
        s_c1[tid] = 0.f; s_c2[tid] = 0.f; s_c3[tid] = 0.f;
        s_diag[tid] = 0.f; s_row0[tid] = 0.f; s_fill[tid] = 0;
    }
    if (tid < 5) s_red[tid] = 0.f;
    if (tid == 0) s_cnt = 0;
    __syncthreads();

    float bce_c = 0.f, ce_c = 0.f, lx_c = 0.f, ly_c = 0.f, lwh_c = 0.f;
    float4 o4 = make_float4(0.f, 0.f, 0.f, 0.f);
    bool m = false;

    // Phase A: BCE + scatter target coords by class index (per-batch permutation).
    if (tid < NN) {
        const float4 t4 = *(const float4*)(tb + (size_t)tid * CC);   // t0..t3
        const float tcls = tb[(size_t)tid * CC + 4];                 // class id (exact small int)
        o4 = *(const float4*)(ob + (size_t)tid * CC);                // p, x, y, wh
        const float t0 = t4.x;
        bce_c = -(t0 * __logf(o4.x) + (1.f - t0) * log1pf(-o4.x));
        m = (t0 != 0.f);
        s_mask[tid] = m ? 1 : 0;
        if (m) {
            const int j = (int)tcls;          // unique per masked row (permutation)
            s_c1[j] = t4.y; s_c2[j] = t4.z; s_c3[j] = t4.w; s_fill[j] = 1;
        } else {
            atomicAdd(&s_cnt, 1);             // unmasked rows contribute exp(0)=1 per channel
        }
    }
    __syncthreads();

    // Phase A2: MSE terms at slot j = tid (filtered row j vs scattered target).
    if (tid < NN) {
        const float f1 = m ? o4.y : 0.f;
        const float f2 = m ? o4.z : 0.f;
        const float f3 = m ? o4.w : 0.f;
        const float d1 = f1 - s_c1[tid];
        const float d2 = f2 - s_c2[tid];
        const float d3 = sqrtf(f3) - sqrtf(s_c3[tid]);
        lx_c = d1 * d1; ly_c = d2 * d2; lwh_c = d3 * d3;
    }

    // Phase B: streaming column exp-sums. Lane l owns channels 4+4l..4+4l+3 (float4),
    // waves stride over rows; unmasked rows skipped (handled via s_cnt).
    const int wave = tid >> 6;
    const int lane = tid & 63;
    if (lane < 63) {
        const float* base = ob + 4 + 4 * lane;
        float4 sum = make_float4(0.f, 0.f, 0.f, 0.f);
        #pragma unroll 4
        for (int n = wave; n < NN; n += NW) {
            if (s_mask[n]) {
                const float4 v = *(const float4*)(base + (size_t)n * CC);
                sum.x += __expf(v.x);
                sum.y += __expf(v.y);
                sum.z += __expf(v.z);
                sum.w += __expf(v.w);
                if ((n >> 2) == lane) {        // diag element x[n, logit-ch n]
                    const int r = n & 3;
                    s_diag[n] = (r == 0) ? v.x : (r == 1) ? v.y : (r == 2) ? v.z : v.w;
                }
                if (n == 0) {                  // row 0 logits (for unfilled slots)
                    s_row0[4*lane+0] = v.x; s_row0[4*lane+1] = v.y;
                    s_row0[4*lane+2] = v.z; s_row0[4*lane+3] = v.w;
                }
            }
        }
        const int o = wave * NN + 4 * lane;
        s_part[o+0] = sum.x; s_part[o+1] = sum.y; s_part[o+2] = sum.z; s_part[o+3] = sum.w;
    }
    __syncthreads();

    // Phase C: combine partials -> lse -> ce contribution per channel.
    if (tid < NN) {
        float s = (float)s_cnt;
        #pragma unroll
        for (int w = 0; w < NW; ++w) s += s_part[w * NN + tid];
        const float lse = __logf(s);
        ce_c = lse - (s_fill[tid] ? s_diag[tid] : s_row0[tid]);
    }

    // Wave-64 shuffle reduction, LDS atomics, 5 global atomics per block.
    #pragma unroll
    for (int off = 32; off > 0; off >>= 1) {
        bce_c += __shfl_down(bce_c, off);
        ce_c  += __shfl_down(ce_c,  off);
        lx_c  += __shfl_down(lx_c,  off);
        ly_c  += __shfl_down(ly_c,  off);
        lwh_c += __shfl_down(lwh_c, off);
    }
    if (lane == 0) {
        atomicAdd(&s_red[0], bce_c);
        atomicAdd(&s_red[1], ce_c);
        atomicAdd(&s_red[2], lx_c);
        atomicAdd(&s_red[3], ly_c);
        atomicAdd(&s_red[4], lwh_c);
    }
    __syncthreads();
    if (tid < 5) atomicAdd(&acc[tid], s_red[tid]);
}

__global__ void detloss_final(const float* __restrict__ acc, float* __restrict__ outv) {
    const float inv = 1.0f / (float)(BB * NN);
    const float bce = acc[0] * inv;
    const float ce  = acc[1] * inv;
    const float lx  = acc[2] * inv;
    const float ly  = acc[3] * inv;
    const float lwh = acc[4] * inv;
    const float mse = lx + ly + 2.f * lwh;
    outv[0] = 10.f * mse + bce + 0.5f * (1.f - bce) + ce;
}

extern "C" void kernel_launch(void* const* d_in, const int* in_sizes, int n_in,
                              void* d_out, int out_size, void* d_ws, size_t ws_size,
                              hipStream_t stream) {
    const float* outp = (const float*)d_in[0];
    const float* tgtp = (const float*)d_in[1];
    float* acc = (float*)d_ws;
    hipMemsetAsync(acc, 0, 5 * sizeof(float), stream);
    detloss_main<<<BB, 1024, 0, stream>>>(outp, tgtp, acc);
    detloss_final<<<1, 1, 0, stream>>>(acc, (float*)d_out);
}

// Round 4
// 235.592 us; speedup vs baseline: 1.1254x; 1.0574x over previous
//
#include <hip/hip_runtime.h>
#include <math.h>

#define BB 512
#define NN 252
#define CC 256
#define NW 16   // waves per block (1024 threads)

typedef float vf4 __attribute__((ext_vector_type(4)));

// ws layout: float part[5][512]  (partial sums per block, no init required)

__global__ __launch_bounds__(1024, 8) void detloss_main(const float* __restrict__ outp,
                                                        const float* __restrict__ tgtp,
                                                        float* __restrict__ part) {
    __shared__ float s_c1[NN], s_c2[NN], s_c3[NN];
    __shared__ float s_diag[NN], s_row0[NN];
    __shared__ float s_part[NW * NN];
    __shared__ float s_red[5];
    __shared__ short s_rows[NN];      // compacted masked-row indices
    __shared__ int s_fill[NN];
    __shared__ int s_nm;              // number of masked rows

    const int b = blockIdx.x;
    const int tid = threadIdx.x;
    const float* ob = outp + (size_t)b * NN * CC;
    const float* tb = tgtp + (size_t)b * NN * CC;

    if (tid < NN) {
        s_c1[tid] = 0.f; s_c2[tid] = 0.f; s_c3[tid] = 0.f;
        s_diag[tid] = 0.f; s_row0[tid] = 0.f; s_fill[tid] = 0;
    }
    if (tid < 5) s_red[tid] = 0.f;
    if (tid == 0) s_nm = 0;
    __syncthreads();

    float bce_c = 0.f, ce_c = 0.f, lx_c = 0.f, ly_c = 0.f, lwh_c = 0.f;
    float4 o4 = make_float4(0.f, 0.f, 0.f, 0.f);
    bool m = false;

    // Phase A: BCE + scatter target coords by class (per-batch permutation) + row compaction.
    if (tid < NN) {
        const float4 t4 = *(const float4*)(tb + (size_t)tid * CC);   // t0..t3
        const float tcls = tb[(size_t)tid * CC + 4];                 // class id (exact small int)
        o4 = *(const float4*)(ob + (size_t)tid * CC);                // p, x, y, wh
        const float t0 = t4.x;
        bce_c = -(t0 * __logf(o4.x) + (1.f - t0) * log1pf(-o4.x));
        m = (t0 != 0.f);
        if (m) {
            const int j = (int)tcls;              // unique per masked row
            s_c1[j] = t4.y; s_c2[j] = t4.z; s_c3[j] = t4.w; s_fill[j] = 1;
            const int slot = atomicAdd(&s_nm, 1);
            s_rows[slot] = (short)tid;
        }
    }
    __syncthreads();

    // Phase A2: MSE terms at slot j = tid.
    if (tid < NN) {
        const float f1 = m ? o4.y : 0.f;
        const float f2 = m ? o4.z : 0.f;
        const float f3 = m ? o4.w : 0.f;
        const float d1 = f1 - s_c1[tid];
        const float d2 = f2 - s_c2[tid];
        const float d3 = sqrtf(f3) - sqrtf(s_c3[tid]);
        lx_c = d1 * d1; ly_c = d2 * d2; lwh_c = d3 * d3;
    }

    // Phase B: branch-free streaming over compacted masked rows.
    // Lane l owns logit channels 4l..4l+3 (float4); waves stride over the row list.
    const int wave = tid >> 6;
    const int lane = tid & 63;
    const int nm = s_nm;
    if (lane < 63) {
        const float* base = ob + 4 + 4 * lane;
        float sx = 0.f, sy = 0.f, sz = 0.f, sw = 0.f;
        for (int i = wave; i < nm; i += NW) {
            const int n = s_rows[i];
            const vf4 v = __builtin_nontemporal_load((const vf4*)(base + (size_t)n * CC));
            sx += __expf(v.x);
            sy += __expf(v.y);
            sz += __expf(v.z);
            sw += __expf(v.w);
            if ((n >> 2) == lane) {            // diag logit x[n, n]
                const int r = n & 3;
                s_diag[n] = (r == 0) ? v.x : (r == 1) ? v.y : (r == 2) ? v.z : v.w;
            }
            if (n == 0) {                      // row-0 logits (for unfilled slots)
                s_row0[4*lane+0] = v.x; s_row0[4*lane+1] = v.y;
                s_row0[4*lane+2] = v.z; s_row0[4*lane+3] = v.w;
            }
        }
        const int o = wave * NN + 4 * lane;
        s_part[o+0] = sx; s_part[o+1] = sy; s_part[o+2] = sz; s_part[o+3] = sw;
    }
    __syncthreads();

    // Phase C: combine partials -> lse -> ce contribution per channel.
    if (tid < NN) {
        float s = (float)(NN - nm);            // unmasked rows contribute exp(0)=1
        #pragma unroll
        for (int w = 0; w < NW; ++w) s += s_part[w * NN + tid];
        const float lse = __logf(s);
        ce_c = lse - (s_fill[tid] ? s_diag[tid] : s_row0[tid]);
    }

    // Block reduction: wave shuffle -> LDS atomics -> per-block partials (no global atomics).
    #pragma unroll
    for (int off = 32; off > 0; off >>= 1) {
        bce_c += __shfl_down(bce_c, off);
        ce_c  += __shfl_down(ce_c,  off);
        lx_c  += __shfl_down(lx_c,  off);
        ly_c  += __shfl_down(ly_c,  off);
        lwh_c += __shfl_down(lwh_c, off);
    }
    if (lane == 0) {
        atomicAdd(&s_red[0], bce_c);
        atomicAdd(&s_red[1], ce_c);
        atomicAdd(&s_red[2], lx_c);
        atomicAdd(&s_red[3], ly_c);
        atomicAdd(&s_red[4], lwh_c);
    }
    __syncthreads();
    if (tid < 5) part[tid * BB + b] = s_red[tid];
}

__global__ __launch_bounds__(512) void detloss_final(const float* __restrict__ part,
                                                     float* __restrict__ outv) {
    __shared__ float s_red[5];
    const int tid = threadIdx.x;
    const int lane = tid & 63;
    if (tid < 5) s_red[tid] = 0.f;
    __syncthreads();

    float v0 = part[0 * BB + tid];
    float v1 = part[1 * BB + tid];
    float v2 = part[2 * BB + tid];
    float v3 = part[3 * BB + tid];
    float v4 = part[4 * BB + tid];
    #pragma unroll
    for (int off = 32; off > 0; off >>= 1) {
        v0 += __shfl_down(v0, off);
        v1 += __shfl_down(v1, off);
        v2 += __shfl_down(v2, off);
        v3 += __shfl_down(v3, off);
        v4 += __shfl_down(v4, off);
    }
    if (lane == 0) {
        atomicAdd(&s_red[0], v0);
        atomicAdd(&s_red[1], v1);
        atomicAdd(&s_red[2], v2);
        atomicAdd(&s_red[3], v3);
        atomicAdd(&s_red[4], v4);
    }
    __syncthreads();
    if (tid == 0) {
        const float inv = 1.0f / (float)(BB * NN);
        const float bce = s_red[0] * inv;
        const float ce  = s_red[1] * inv;
        const float lx  = s_red[2] * inv;
        const float ly  = s_red[3] * inv;
        const float lwh = s_red[4] * inv;
        const float mse = lx + ly + 2.f * lwh;
        outv[0] = 10.f * mse + bce + 0.5f * (1.f - bce) + ce;
    }
}

extern "C" void kernel_launch(void* const* d_in, const int* in_sizes, int n_in,
                              void* d_out, int out_size, void* d_ws, size_t ws_size,
                              hipStream_t stream) {
    const float* outp = (const float*)d_in[0];
    const float* tgtp = (const float*)d_in[1];
    float* part = (float*)d_ws;     // 5*512 floats, fully written by detloss_main
    detloss_main<<<BB, 1024, 0, stream>>>(outp, tgtp, part);
    detloss_final<<<1, 512, 0, stream>>>(part, (float*)d_out);
}